// Round 11
// baseline (35.006 us; speedup 1.0000x reference)
//
#include <hip/hip_runtime.h>
#include <hip/hip_bf16.h>

#define N_PTS 4096
#define D_EMB 64
#define BT    64                                   // block tile (4 waves x 32x32)
#define NPART ((N_PTS / BT) * (N_PTS / BT))        // 4096 block partials

typedef __attribute__((ext_vector_type(8))) short bf16x8;  // 8 bf16 = 4 VGPR
typedef __attribute__((ext_vector_type(4))) float f32x4;   // MFMA 16x16 acc

// ---------------------------------------------------------------------------
// Fused prep: bf16 hi/lo split + exact f32 row squared-norms.
// ---------------------------------------------------------------------------
__global__ void prep_kernel(const float* __restrict__ mapping,
                            ushort* __restrict__ Mhi,
                            ushort* __restrict__ Mlo,
                            float* __restrict__ nrm) {
  const int row = blockIdx.x;
  const int l = threadIdx.x;          // 0..63
  const int idx = row * D_EMB + l;
  const float x = mapping[idx];
  __hip_bfloat16 h = __float2bfloat16(x);
  const float hf = __bfloat162float(h);
  __hip_bfloat16 lo = __float2bfloat16(x - hf);
  Mhi[idx] = *reinterpret_cast<ushort*>(&h);
  Mlo[idx] = *reinterpret_cast<ushort*>(&lo);
  float s = x * x;
  #pragma unroll
  for (int off = 32; off > 0; off >>= 1) s += __shfl_down(s, off);
  if (l == 0) nrm[row] = s;
}

// ---------------------------------------------------------------------------
// 64x64 tile: overlap-structured gram + distortion.
// dot = Hj.Hi + Hj.Li + Lj.Hi (Li.Lj dropped; absmax 0.0 since R6).
//
// R10 post-mortem: dense access fixed the scatter but the phase structure
// was fully serial (D reads naked at the tail, staging drains serial with
// MFMA) -> ~3x over the work model. THIS round (T14 async-split):
//   1. issue D-tile loads into REGISTERS first (dense 4-row x 256B bursts),
//   2. issue panel staging via global_load_lds (source pre-swizzled
//      c^=(r&7); LDS linear — rule 21),
//   3. ONE barrier drains both concurrent streams (D latency hidden),
//   4. gram: swizzled ds_read_b128 frags + 24 MFMA (layouts HW-verified),
//   5. dump gram to LDS (reuse panel space; 32KB total -> 5 blocks/CU),
//   6. pure reg/LDS epilogue, block-level partial reduce (no atomics).
// 4096 blocks = 16/CU demanded -> deep inter-block overlap.
// R7 lesson: frag loads grouped, never phased into load->mfma pairs.
// R2/R3 lesson: no min-waves launch_bounds arg.
// ---------------------------------------------------------------------------
__global__ __launch_bounds__(256) void distortion_main(
    const ushort* __restrict__ Mhi, const ushort* __restrict__ Mlo,
    const float* __restrict__ Dm, const float* __restrict__ nrm,
    double* __restrict__ part) {
  __shared__ __align__(16) char smem[32768];   // 4 panels; later gram dump
  ushort* span = (ushort*)smem;   // [p][r][cs]: p*4096 + r*64 + cs*8 (ushorts)
  float*  sg   = (float*)smem;    // gram dump: 64 rows x 64 cols f32 (16KB)

  const int t = threadIdx.x;
  const int w = t >> 6, l = t & 63;
  const int r16 = l & 15;        // fragment row/col within 16
  const int kg  = l >> 4;        // k-group 0..3
  const int wr = w >> 1, wc = w & 1;
  const int i0 = blockIdx.y * BT;
  const int j0 = blockIdx.x * BT;

  // ---- (1) EARLY dense D-tile + col-norm loads into registers.
  // Wave w owns epilogue slab rows i_b = w*16 .. w*16+15, all 64 cols.
  const int jc   = l & 15;       // float4 col-chunk 0..15
  const int isub = l >> 4;       // row-within-iter 0..3
  const int gj0  = j0 + jc * 4;
  const int irow0 = w * 16;
  float4 D4[4];
  #pragma unroll
  for (int it = 0; it < 4; ++it) {
    const int gi = i0 + irow0 + it * 4 + isub;
    D4[it] = *(const float4*)(Dm + (size_t)gi * N_PTS + gj0);
  }
  const float4 rB4 = *(const float4*)(nrm + gj0);

  // ---- (2) stage 4 panels (64r x 64 bf16, 8KB each): p0 AH, p1 AL,
  //      p2 BH, p3 BL. LDS linear; source chunk c = cs ^ (r&7).
  #pragma unroll
  for (int q = 0; q < 8; ++q) {
    const int s  = q * 256 + t;      // 16B slot 0..2047
    const int p  = s >> 9;           // panel
    const int sp = s & 511;
    const int r  = sp >> 3;          // row 0..63
    const int cs = sp & 7;           // stored chunk
    const int c  = cs ^ (r & 7);     // source chunk (involution)
    const ushort* base = (p & 1) ? Mlo : Mhi;
    const int row = ((p < 2) ? i0 : j0) + r;
    const ushort* g = base + (size_t)row * D_EMB + c * 8;
    char* ldst = smem + q * 4096 + w * 1024;   // wave-uniform + lane*16
    __builtin_amdgcn_global_load_lds(
        (const __attribute__((address_space(1))) void*)g,
        (__attribute__((address_space(3))) void*)ldst, 16, 0, 0);
  }
  __syncthreads();   // (3) single drain: staging AND D regs (concurrent)

  // ---- (4) gram: 32x32 per wave, K=64 = 2 MFMA k-steps
  f32x4 acc[2][2] = {};  // rows gj = j0+wc*32+n*16+kg*4+reg, cols gi = i0+wr*32+m*16+r16

  #pragma unroll
  for (int ks = 0; ks < 2; ++ks) {
    bf16x8 aH[2], aL[2], bH[2], bL[2];   // a = i-panel, b = j-panel
    #pragma unroll
    for (int m = 0; m < 2; ++m) {
      const int r  = wr * 32 + m * 16 + r16;
      const int cs = (ks * 4 + kg) ^ (r & 7);
      aH[m] = *(const bf16x8*)(span + 0 * 4096 + r * 64 + cs * 8);
      aL[m] = *(const bf16x8*)(span + 1 * 4096 + r * 64 + cs * 8);
    }
    #pragma unroll
    for (int n = 0; n < 2; ++n) {
      const int r  = wc * 32 + n * 16 + r16;
      const int cs = (ks * 4 + kg) ^ (r & 7);
      bH[n] = *(const bf16x8*)(span + 2 * 4096 + r * 64 + cs * 8);
      bL[n] = *(const bf16x8*)(span + 3 * 4096 + r * 64 + cs * 8);
    }
    #pragma unroll
    for (int m = 0; m < 2; ++m)
      #pragma unroll
      for (int n = 0; n < 2; ++n) {
        acc[m][n] = __builtin_amdgcn_mfma_f32_16x16x32_bf16(
            bH[n], aH[m], acc[m][n], 0, 0, 0);   // Hj.Hi
        acc[m][n] = __builtin_amdgcn_mfma_f32_16x16x32_bf16(
            bH[n], aL[m], acc[m][n], 0, 0, 0);   // Hj.Li
        acc[m][n] = __builtin_amdgcn_mfma_f32_16x16x32_bf16(
            bL[n], aH[m], acc[m][n], 0, 0, 0);   // Lj.Hi
      }
  }

  __syncthreads();   // all frag reads done -> panel space reusable

  // ---- (5) dump gram to LDS, swizzle slot = jc4 ^ (i_b&7)
  #pragma unroll
  for (int m = 0; m < 2; ++m) {
    const int i_b = wr * 32 + m * 16 + r16;
    #pragma unroll
    for (int n = 0; n < 2; ++n) {
      const int jc4 = wc * 8 + n * 4 + kg;
      *(f32x4*)(sg + i_b * 64 + ((jc4 ^ (i_b & 7)) * 4)) = acc[m][n];
    }
  }
  __syncthreads();

  // ---- (6) epilogue: gram from LDS, D from registers (already drained)
  float s1 = 0.f, s2 = 0.f, s3 = 0.f, s4 = 0.f;
  #pragma unroll
  for (int it = 0; it < 4; ++it) {
    const int i_b = irow0 + it * 4 + isub;
    const int gi = i0 + i_b;
    const float rA = nrm[gi];
    const float4 g4 = *(const float4*)(sg + i_b * 64 + ((jc ^ (i_b & 7)) * 4));
    const float4 Dv4 = D4[it];
    #pragma unroll
    for (int r = 0; r < 4; ++r) {
      const float Dv  = (r == 0) ? Dv4.x : (r == 1) ? Dv4.y : (r == 2) ? Dv4.z : Dv4.w;
      const float rB  = (r == 0) ? rB4.x : (r == 1) ? rB4.y : (r == 2) ? rB4.z : rB4.w;
      const float dot = (r == 0) ? g4.x  : (r == 1) ? g4.y  : (r == 2) ? g4.z  : g4.w;
      const float sq = fmaxf(rA + rB - 2.f * dot, 0.f);
      float dd = __builtin_amdgcn_sqrtf(sq);
      const bool diag = (gi == gj0 + r);
      if (diag) dd = 0.f;                      // exact: ||x-x|| = 0
      const float denom = Dv + (diag ? 1.f : 0.f) + 1e-8f;
      const float rd = __builtin_amdgcn_rcpf(denom);
      const float av = dd * rd;                // a = d/denom
      const float bv = Dv * rd;                // b = D/denom
      s1 += av;
      s2 = fmaf(av, av, s2);
      s3 = fmaf(av, bv, s3);
      s4 = fmaf(bv, bv, s4);
    }
  }

  // ---- wave shuffle reduce, then block-level reduce, ONE write-set/block
  #pragma unroll
  for (int off = 32; off > 0; off >>= 1) {
    s1 += __shfl_down(s1, off);
    s2 += __shfl_down(s2, off);
    s3 += __shfl_down(s3, off);
    s4 += __shfl_down(s4, off);
  }
  float* redv = (float*)(smem + 16384);   // past the gram dump region
  if (l == 0) {
    redv[w * 4 + 0] = s1; redv[w * 4 + 1] = s2;
    redv[w * 4 + 2] = s3; redv[w * 4 + 3] = s4;
  }
  __syncthreads();
  if (t < 4) {
    const double v = (double)redv[0 * 4 + t] + (double)redv[1 * 4 + t] +
                     (double)redv[2 * 4 + t] + (double)redv[3 * 4 + t];
    const int bid = blockIdx.y * gridDim.x + blockIdx.x;
    part[t * NPART + bid] = v;
  }
}

// ---------------------------------------------------------------------------
// Reduce 4 x NPART partials; emit sum(dist) = s^2*S2 - 2 s S3 + S4, s=S1/S2.
// ---------------------------------------------------------------------------
__global__ __launch_bounds__(1024) void distortion_final(
    const double* __restrict__ part, float* __restrict__ out) {
  __shared__ double red[16][4];
  const int t = threadIdx.x;
  double s[4];
  #pragma unroll
  for (int k = 0; k < 4; ++k) {
    double v = 0.0;
    #pragma unroll
    for (int c = 0; c < NPART / 1024; ++c) v += part[k * NPART + c * 1024 + t];
    s[k] = v;
  }
  #pragma unroll
  for (int off = 32; off > 0; off >>= 1)
    #pragma unroll
    for (int k = 0; k < 4; ++k) s[k] += __shfl_down(s[k], off);
  const int w = t >> 6, l = t & 63;
  if (l == 0) {
    #pragma unroll
    for (int k = 0; k < 4; ++k) red[w][k] = s[k];
  }
  __syncthreads();
  if (t == 0) {
    double S0 = 0, S1 = 0, S2 = 0, S3 = 0;
    #pragma unroll
    for (int ww = 0; ww < 16; ++ww) {
      S0 += red[ww][0]; S1 += red[ww][1]; S2 += red[ww][2]; S3 += red[ww][3];
    }
    const double sc = S0 / S1;
    const double r = (sc * sc * S1 - 2.0 * sc * S2 + S3) /
                     ((double)N_PTS * (double)N_PTS - (double)N_PTS);
    out[0] = (float)r;
  }
}

extern "C" void kernel_launch(void* const* d_in, const int* in_sizes, int n_in,
                              void* d_out, int out_size, void* d_ws, size_t ws_size,
                              hipStream_t stream) {
  const float* mapping = (const float*)d_in[0];
  const float* Dm = (const float*)d_in[1];
  float* out = (float*)d_out;
  // ws layout: nrm 16KB | part 128KB | Mhi 512KB | Mlo 512KB  (~1.2 MB)
  float* nrm = (float*)d_ws;
  double* part = (double*)((char*)d_ws + 16384);
  ushort* Mhi = (ushort*)((char*)d_ws + 16384 + 131072);
  ushort* Mlo = (ushort*)((char*)d_ws + 16384 + 131072 + 524288);

  prep_kernel<<<dim3(N_PTS), dim3(64), 0, stream>>>(mapping, Mhi, Mlo, nrm);
  distortion_main<<<dim3(N_PTS / BT, N_PTS / BT), dim3(256), 0, stream>>>(
      Mhi, Mlo, Dm, nrm, part);
  distortion_final<<<1, 1024, 0, stream>>>(part, out);
}